// Round 10
// baseline (821.575 us; speedup 1.0000x reference)
//
#include <hip/hip_runtime.h>
#include <type_traits>

#define N_NODES 100000
#define N_EDGES 1600000
#define NFEAT 512
#define NHID 256
#define NCLASS 40
#define NPAD 100096    // 391 * 256
#define NPAD2 100352   // 196 * 512 (rowptr2 entries)

// bucket sort geometry
#define NBUCK 196     // buckets of 512 rows: (99999>>9)=195 -> 196 buckets
#define BROWS 512
#define NBLK_BIN 256
#define EPB 6250      // 256 * 6250 == 1,600,000 exactly

// padded colidx: rows padded to multiple of 4; per-bucket slack 1600
#define CDUM 1916000          // dummy 4-int segment (cols = N_NODES)
#define COLN 1916032          // colidx allocation (ints)

// class-split power iteration: 40 = 32 (pass A) + 8 (pass B)
#define ZA (N_NODES * 32)   // dummy zero-row element offset, pass A
#define ZB (N_NODES * 8)    // dummy zero-row element offset, pass B
#define BLK_A 1563          // 6,250 waves x 16 rows (tail-guarded)
#define BLK_B 391           // 1,564 waves x 64 rows (last partial)

typedef __bf16 bf16;
typedef __bf16 bf16x8 __attribute__((ext_vector_type(8)));
typedef __bf16 bf16x4 __attribute__((ext_vector_type(4)));
typedef float f32x4 __attribute__((ext_vector_type(4)));
typedef int i32x4 __attribute__((ext_vector_type(4)));

// raw barrier without the compiler's vmcnt(0) drain: in-flight global
// prefetch survives; lgkmcnt(0) covers ds_write visibility + cross-wave WAR.
__device__ __forceinline__ void barrier_keep_vmem() {
    asm volatile("s_waitcnt lgkmcnt(0)" ::: "memory");
    __builtin_amdgcn_s_barrier();
}

// ---------------- CSR build via 2-level counting sort ----------------

__global__ __launch_bounds__(256) void bin_count(const int* __restrict__ rows,
                                                 int* __restrict__ bcnt) {
    __shared__ int hist[NBUCK];
    int t = threadIdx.x, b = blockIdx.x;
    for (int i = t; i < NBUCK; i += 256) hist[i] = 0;
    __syncthreads();
    int base = b * EPB;
    for (int i = t; i < EPB; i += 256) atomicAdd(&hist[rows[base + i] >> 9], 1);
    __syncthreads();
    for (int i = t; i < NBUCK; i += 256) bcnt[i * NBLK_BIN + b] = hist[i];
}

__global__ __launch_bounds__(256) void bin_scan(const int* __restrict__ bcnt,
                                                int* __restrict__ boff2,
                                                int* __restrict__ btot) {
    __shared__ int sh[256];
    int t = threadIdx.x, bu = blockIdx.x;
    int v = bcnt[bu * 256 + t];
    sh[t] = v;
    __syncthreads();
    for (int off = 1; off < 256; off <<= 1) {
        int x = (t >= off) ? sh[t - off] : 0;
        __syncthreads();
        sh[t] += x;
        __syncthreads();
    }
    boff2[t * NBUCK + bu] = sh[t] - v;  // exclusive, [block][bucket] layout
    if (t == 255) btot[bu] = sh[255];
}

__global__ __launch_bounds__(256) void base_scan(const int* __restrict__ btot,
                                                 int* __restrict__ bbase) {
    __shared__ int sh[256];
    int t = threadIdx.x;
    int v = (t < NBUCK) ? btot[t] : 0;
    sh[t] = v;
    __syncthreads();
    for (int off = 1; off < 256; off <<= 1) {
        int x = (t >= off) ? sh[t - off] : 0;
        __syncthreads();
        sh[t] += x;
        __syncthreads();
    }
    if (t < NBUCK) bbase[t] = sh[t] - v;
    if (t == NBUCK - 1) bbase[NBUCK] = sh[t];  // == N_EDGES
}

__global__ __launch_bounds__(256) void bin_scatter(const int* __restrict__ rows,
                                                   const int* __restrict__ cols,
                                                   const int* __restrict__ boff2,
                                                   const int* __restrict__ bbase,
                                                   int* __restrict__ binned) {
    __shared__ int cur[NBUCK];
    int t = threadIdx.x, b = blockIdx.x;
    for (int i = t; i < NBUCK; i += 256) cur[i] = bbase[i] + boff2[b * NBUCK + i];
    __syncthreads();
    int base = b * EPB;
    for (int i = t; i < EPB; i += 256) {
        int r = rows[base + i], c = cols[base + i];
        int pos = atomicAdd(&cur[r >> 9], 1);
        binned[pos] = ((r & 511) << 17) | c;  // col < 100000 < 2^17
    }
}

// Pass 5: one block per bucket. Per-row counts + PADDED (multiple-of-4,
// 16B-aligned) prefix in LDS; produces rowptr2 (start,end) and dinv; pads
// each row's tail with dummy col N_NODES; scatters cols.
__global__ __launch_bounds__(256) void bucket_csr(const int* __restrict__ binned,
                                                  const int* __restrict__ bbase,
                                                  int2* __restrict__ rowptr2,
                                                  int* __restrict__ colidx,
                                                  float* __restrict__ dinv) {
    __shared__ int cnt[BROWS];
    __shared__ int pref[BROWS];
    __shared__ int psum[256];
    int t = threadIdx.x, bu = blockIdx.x;
    cnt[t] = 0;
    cnt[t + 256] = 0;
    __syncthreads();
    int base = bbase[bu], end = bbase[bu + 1];
    for (int i = base + t; i < end; i += 256) atomicAdd(&cnt[binned[i] >> 17], 1);
    __syncthreads();
    int c0 = cnt[2 * t], c1 = cnt[2 * t + 1];
    int p0 = (c0 + 3) & ~3, p1 = (c1 + 3) & ~3;
    psum[t] = p0 + p1;
    __syncthreads();
    for (int off = 1; off < 256; off <<= 1) {
        int x = (t >= off) ? psum[t - off] : 0;
        __syncthreads();
        psum[t] += x;
        __syncthreads();
    }
    int pex = psum[t] - (p0 + p1);
    pref[2 * t] = pex;
    pref[2 * t + 1] = pex + p0;
    __syncthreads();
    int pbase = (base & ~3) + bu * 1600;   // 4-aligned, slack-separated
#pragma unroll
    for (int j = 0; j < 2; j++) {
        int idx = t + j * 256;
        int grow = bu * BROWS + idx;
        int rc = cnt[idx];
        int st = pbase + pref[idx];
        int en = st + ((rc + 3) & ~3);
        if (grow < N_NODES) {
            rowptr2[grow] = make_int2(st, en);
            dinv[grow] = 0.5f / (float)(rc + 1);  // pre-halved, +1 self-loop
            for (int k = st + rc; k < en; k++) colidx[k] = N_NODES;  // dummy pad
        } else {
            rowptr2[grow] = make_int2(0, 0);      // grow < NPAD2 always
        }
        pref[idx] = st;  // absolute cursor
    }
    __syncthreads();
    for (int i = base + t; i < end; i += 256) {
        int v = binned[i];
        int pos = atomicAdd(&pref[v >> 17], 1);
        colidx[pos] = v & 0x1FFFF;
    }
}

// ---------------- weight conversion ----------------

__global__ void cvt_f2b(const float* __restrict__ a, bf16* __restrict__ b, int n) {
    int i = blockIdx.x * 256 + threadIdx.x;
    if (i < n) b[i] = (bf16)a[i];
}

__global__ void pad_w3(const float* __restrict__ W3, const float* __restrict__ b3,
                       bf16* __restrict__ W3p, float* __restrict__ b3p) {
    int i = blockIdx.x * 256 + threadIdx.x;  // over 64*256
    int r = i >> 8;
    W3p[i] = (bf16)((r < NCLASS) ? W3[(size_t)r * 256 + (i & 255)] : 0.f);
    if (i < 64) b3p[i] = (i < NCLASS) ? b3[i] : 0.f;
}

// zero dummy gather rows + dummy colidx segment
__global__ void zero_dummy(bf16* vAi, bf16* vA0, bf16* vA1,
                           bf16* vBi, bf16* vB0, bf16* vB1,
                           int* colidx) {
    int i = threadIdx.x;
    if (i < 32) {
        vAi[(size_t)ZA + i] = (bf16)0.f;
        vA0[(size_t)ZA + i] = (bf16)0.f;
        vA1[(size_t)ZA + i] = (bf16)0.f;
    }
    if (i < 8) {
        vBi[(size_t)ZB + i] = (bf16)0.f;
        vB0[(size_t)ZB + i] = (bf16)0.f;
        vB1[(size_t)ZB + i] = (bf16)0.f;
        colidx[CDUM + i] = N_NODES;
    }
}

// ---------------- bf16 MFMA GEMM-NT, 2-set deep-pipelined ----------------
// Iteration t: STORE tile t+1 (regs loaded 2 iterations ago -> compiler's
// counted vmcnt), re-LOAD that set with tile t+3, COMPUTE tile t from LDS.
// Barriers via barrier_keep_vmem(): no vmcnt(0) drain, prefetch stays in
// flight across the barrier (the reason R3/R9 pipelining nulled).

template <int BN, typename AT, bool RELU, int OUTMODE>
__global__ __launch_bounds__(256) void gemm_mfma(const AT* __restrict__ A,
                                                 const bf16* __restrict__ B,
                                                 const float* __restrict__ bias,
                                                 bf16* __restrict__ Cb,
                                                 float* __restrict__ hA,
                                                 float* __restrict__ hB,
                                                 bf16* __restrict__ vA0,
                                                 bf16* __restrict__ vB0,
                                                 int M, int K, int Nout) {
    constexpr int LDT = 40;
    constexpr int WTM = (BN == 128) ? 64 : 32;
    constexpr int MI = WTM / 16;
    constexpr int WMC = 128 / WTM;
    constexpr int BG = BN / 64;
    constexpr bool AF32 = std::is_same<AT, float>::value;
    __shared__ bf16 As[2][128 * LDT];
    __shared__ bf16 Bs[2][BN * LDT];

    int tid = threadIdx.x;
    int wave = tid >> 6, lane = tid & 63;
    int waveM = wave % WMC, waveN = wave / WMC;
    int lc = lane & 15, lq = lane >> 4;

    f32x4 acc[MI][4];
#pragma unroll
    for (int i = 0; i < MI; i++)
#pragma unroll
        for (int j = 0; j < 4; j++) acc[i][j] = (f32x4){0.f, 0.f, 0.f, 0.f};

    int sr = tid >> 2;
    int sc = (tid & 3) * 8;

    // two staging register sets (static names, rule #20)
    float4 paE[2][2], paO[2][2];
    bf16x8 baE[2], baO[2];
    bf16x8 bbE[BG], bbO[BG];

    auto LOAD = [&](int k0, float4 (&pa)[2][2], bf16x8 (&ba)[2], bf16x8 (&bb)[BG]) {
#pragma unroll
        for (int g = 0; g < 2; g++) {
            int grow = blockIdx.y * 128 + sr + g * 64;
            if (grow > M - 1) grow = M - 1;  // clamp (results discarded by store guard)
            if constexpr (AF32) {
                const float* ap = A + (size_t)grow * K + k0 + sc;
                pa[g][0] = *(const float4*)ap;
                pa[g][1] = *(const float4*)(ap + 4);
            } else {
                ba[g] = *(const bf16x8*)(A + (size_t)grow * K + k0 + sc);
            }
        }
#pragma unroll
        for (int g = 0; g < BG; g++) {
            int brow = blockIdx.x * BN + sr + g * 64;
            bb[g] = *(const bf16x8*)(B + (size_t)brow * K + k0 + sc);
        }
    };
    auto STORE = [&](int buf, float4 (&pa)[2][2], bf16x8 (&ba)[2], bf16x8 (&bb)[BG]) {
#pragma unroll
        for (int g = 0; g < 2; g++) {
            bf16x8 val;
            if constexpr (AF32) {
                val[0] = (bf16)pa[g][0].x; val[1] = (bf16)pa[g][0].y;
                val[2] = (bf16)pa[g][0].z; val[3] = (bf16)pa[g][0].w;
                val[4] = (bf16)pa[g][1].x; val[5] = (bf16)pa[g][1].y;
                val[6] = (bf16)pa[g][1].z; val[7] = (bf16)pa[g][1].w;
            } else {
                val = ba[g];
            }
            *(bf16x8*)&As[buf][(sr + g * 64) * LDT + sc] = val;
        }
#pragma unroll
        for (int g = 0; g < BG; g++)
            *(bf16x8*)&Bs[buf][(sr + g * 64) * LDT + sc] = bb[g];
    };
    auto COMPUTE = [&](int cb) {
        bf16x8 af[MI], bfr[4];
#pragma unroll
        for (int i = 0; i < MI; i++)
            af[i] = *(const bf16x8*)&As[cb][(waveM * WTM + i * 16 + lc) * LDT + lq * 8];
#pragma unroll
        for (int j = 0; j < 4; j++)
            bfr[j] = *(const bf16x8*)&Bs[cb][(waveN * 64 + j * 16 + lc) * LDT + lq * 8];
#pragma unroll
        for (int i = 0; i < MI; i++)
#pragma unroll
            for (int j = 0; j < 4; j++)
                acc[i][j] = __builtin_amdgcn_mfma_f32_16x16x32_bf16(af[i], bfr[j], acc[i][j], 0, 0, 0);
    };

    int nt = K / 32;   // 16 or 8, always even and > 2
    // prologue: buf0 <- tile0; setE <- tile1 (in flight); setO <- tile2 (in flight)
    LOAD(0, paE, baE, bbE);
    STORE(0, paE, baE, bbE);
    LOAD(32, paE, baE, bbE);
    LOAD(64, paO, baO, bbO);
    barrier_keep_vmem();
    for (int t = 0; t < nt; t += 2) {
        // even iter t: store tile t+1 (setE), refill setE <- tile t+3, compute tile t (buf0)
        STORE(1, paE, baE, bbE);
        if (t + 3 < nt) LOAD((t + 3) * 32, paE, baE, bbE);
        COMPUTE(0);
        barrier_keep_vmem();
        // odd iter t+1: store tile t+2 (setO), refill setO <- tile t+4, compute tile t+1 (buf1)
        if (t + 2 < nt) STORE(0, paO, baO, bbO);
        if (t + 4 < nt) LOAD((t + 4) * 32, paO, baO, bbO);
        COMPUTE(1);
        barrier_keep_vmem();
    }

    // epilogue
#pragma unroll
    for (int i = 0; i < MI; i++) {
        int row0 = blockIdx.y * 128 + waveM * WTM + i * 16 + lq * 4;
#pragma unroll
        for (int j = 0; j < 4; j++) {
            int colL = waveN * 64 + j * 16 + lc;
            int col = blockIdx.x * BN + colL;
            float bv = bias[col];
#pragma unroll
            for (int reg = 0; reg < 4; reg++) {
                int rr = row0 + reg;
                if (rr < M) {
                    float v = acc[i][j][reg] + bv;
                    if (RELU) v = v > 0.f ? v : 0.f;
                    if (OUTMODE == 0) {
                        Cb[(size_t)rr * Nout + col] = (bf16)v;
                    } else {
                        if (col < 32) {
                            hA[(size_t)rr * 32 + col] = 0.5f * v;
                            vA0[(size_t)rr * 32 + col] = (bf16)v;
                        } else if (col < NCLASS) {
                            hB[(size_t)rr * 8 + (col - 32)] = 0.5f * v;
                            vB0[(size_t)rr * 8 + (col - 32)] = (bf16)v;
                        }
                    }
                }
            }
        }
    }
}

// ---------------- wide-load pipelined class-split SpMM ----------------
// Pass A and pass B are fully independent chains (disjoint classes); they
// run as SEPARATE kernels so pass B's 1.6 MB v-buffer stays L2-resident
// instead of being thrashed by pass A's 102 MB/iter random line traffic.

// Pass A: 32 classes, lane=8 cls (16B), 4 lanes/row, 16 rows/wave.
__global__ __launch_bounds__(256) void spmm_A(const bf16* __restrict__ vA,
                                              const float* __restrict__ hA,
                                              const int2* __restrict__ rowptr2,
                                              const int* __restrict__ colidx,
                                              const float* __restrict__ dinv,
                                              bf16* __restrict__ oA,
                                              float* __restrict__ outF,
                                              int final_it) {
    int lane = threadIdx.x & 63;
    const int* cdum = colidx + CDUM;
    int w = blockIdx.x * 4 + (threadIdx.x >> 6);
    int sub = lane & 3;
    int r = w * 16 + (lane >> 2);         // 16 rows per wave
    if (r >= N_NODES) return;             // uniform for tail waves
    int2 se = rowptr2[r];
    int sx = se.x, d = se.y - se.x;       // padded degree, multiple of 4
    int m = d;
#pragma unroll
    for (int off = 4; off < 64; off <<= 1) {
        int x = __shfl_xor(m, off);
        m = m > x ? m : x;
    }
    float4 hv0 = *(const float4*)(hA + (size_t)r * 32 + sub * 8);      // pre-halved
    float4 hv1 = *(const float4*)(hA + (size_t)r * 32 + sub * 8 + 4);
    float dv = dinv[r];
    bf16x8 sv = *(const bf16x8*)(vA + (size_t)r * 32 + sub * 8);  // self-loop
    float a[8];
#pragma unroll
    for (int k = 0; k < 8; k++) a[k] = (float)sv[k];
    // pipeline primer: idx batches 0 and 1; gathers for batch 0
    i32x4 cc = *(const i32x4*)(d > 0 ? colidx + sx : cdum);
    i32x4 cn = *(const i32x4*)(4 < d ? colidx + sx + 4 : cdum);
    bf16x8 G0 = *(const bf16x8*)(vA + (size_t)cc[0] * 32 + sub * 8);
    bf16x8 G1 = *(const bf16x8*)(vA + (size_t)cc[1] * 32 + sub * 8);
    bf16x8 G2 = *(const bf16x8*)(vA + (size_t)cc[2] * 32 + sub * 8);
    bf16x8 G3 = *(const bf16x8*)(vA + (size_t)cc[3] * 32 + sub * 8);
    int m8 = (m + 7) & ~7;
    for (int i = 0; i < m8; i += 8) {
        i32x4 ci8 = *(const i32x4*)((i + 8 < d) ? colidx + sx + i + 8 : cdum);
        bf16x8 H0 = *(const bf16x8*)(vA + (size_t)cn[0] * 32 + sub * 8);
        bf16x8 H1 = *(const bf16x8*)(vA + (size_t)cn[1] * 32 + sub * 8);
        bf16x8 H2 = *(const bf16x8*)(vA + (size_t)cn[2] * 32 + sub * 8);
        bf16x8 H3 = *(const bf16x8*)(vA + (size_t)cn[3] * 32 + sub * 8);
#pragma unroll
        for (int k = 0; k < 8; k++)
            a[k] += ((float)G0[k] + (float)G1[k]) + ((float)G2[k] + (float)G3[k]);
        cn = *(const i32x4*)((i + 12 < d) ? colidx + sx + i + 12 : cdum);
        G0 = *(const bf16x8*)(vA + (size_t)ci8[0] * 32 + sub * 8);
        G1 = *(const bf16x8*)(vA + (size_t)ci8[1] * 32 + sub * 8);
        G2 = *(const bf16x8*)(vA + (size_t)ci8[2] * 32 + sub * 8);
        G3 = *(const bf16x8*)(vA + (size_t)ci8[3] * 32 + sub * 8);
#pragma unroll
        for (int k = 0; k < 8; k++)
            a[k] += ((float)H0[k] + (float)H1[k]) + ((float)H2[k] + (float)H3[k]);
    }
    float res[8];
    res[0] = dv * a[0] + hv0.x; res[1] = dv * a[1] + hv0.y;
    res[2] = dv * a[2] + hv0.z; res[3] = dv * a[3] + hv0.w;
    res[4] = dv * a[4] + hv1.x; res[5] = dv * a[5] + hv1.y;
    res[6] = dv * a[6] + hv1.z; res[7] = dv * a[7] + hv1.w;
    if (final_it) {
        *(float4*)(outF + (size_t)r * NCLASS + sub * 8) = (float4){res[0], res[1], res[2], res[3]};
        *(float4*)(outF + (size_t)r * NCLASS + sub * 8 + 4) = (float4){res[4], res[5], res[6], res[7]};
    } else {
        bf16x8 o;
#pragma unroll
        for (int k = 0; k < 8; k++) o[k] = (bf16)res[k];
        *(bf16x8*)(oA + (size_t)r * 32 + sub * 8) = o;
    }
}

// Pass B: 8 classes, lane=whole row (16B), 64 rows/wave. vB is 1.6 MB ->
// L2-resident when run in its own launch chain.
__global__ __launch_bounds__(256) void spmm_B(const bf16* __restrict__ vB,
                                              const float* __restrict__ hB,
                                              const int2* __restrict__ rowptr2,
                                              const int* __restrict__ colidx,
                                              const float* __restrict__ dinv,
                                              bf16* __restrict__ oB,
                                              float* __restrict__ outF,
                                              int final_it) {
    int lane = threadIdx.x & 63;
    const int* cdum = colidx + CDUM;
    int w = blockIdx.x * 4 + (threadIdx.x >> 6);
    int r = w * 64 + lane;                          // 0..100095 (< NPAD2)
    int rz = (r < N_NODES) ? r : 0;
    int2 se = rowptr2[r];                           // (0,0) for r>=N_NODES
    int sx = se.x, d = se.y - se.x;
    int m = d;
#pragma unroll
    for (int off = 1; off < 64; off <<= 1) {
        int x = __shfl_xor(m, off);
        m = m > x ? m : x;
    }
    float4 h0 = *(const float4*)(hB + (size_t)rz * 8);
    float4 h1 = *(const float4*)(hB + (size_t)rz * 8 + 4);
    float dv = dinv[rz];
    bf16x8 sv = *(const bf16x8*)(vB + (size_t)rz * 8);  // self-loop
    float a[8];
#pragma unroll
    for (int k = 0; k < 8; k++) a[k] = (float)sv[k];
    i32x4 cc = *(const i32x4*)(d > 0 ? colidx + sx : cdum);
    i32x4 cn = *(const i32x4*)(4 < d ? colidx + sx + 4 : cdum);
    bf16x8 G0 = *(const bf16x8*)(vB + (size_t)cc[0] * 8);
    bf16x8 G1 = *(const bf16x8*)(vB + (size_t)cc[1] * 8);
    bf16x8 G2 = *(const bf16x8*)(vB + (size_t)cc[2] * 8);
    bf16x8 G3 = *(const bf16x8*)(vB + (size_t)cc[3] * 8);
    int m8 = (m + 7) & ~7;
    for (int i = 0; i < m8; i += 8) {
        i32x4 ci8 = *(const i32x4*)((i + 8 < d) ? colidx + sx + i + 8 : cdum);
        bf16x8 H0 = *(const bf16x8*)(vB + (size_t)cn[0] * 8);
        bf16x8 H1 = *(const bf16x8*)(vB + (size_t)cn[1] * 8);
        bf16x8 H2 = *(const bf16x8*)(vB + (size_t)cn[2] * 8);
        bf16x8 H3 = *(const bf16x8*)(vB + (size_t)cn[3] * 8);
#pragma unroll
        for (int k = 0; k < 8; k++)
            a[k] += ((float)G0[k] + (float)G1[k]) + ((float)G2[k] + (float)G3[k]);
        cn = *(const i32x4*)((i + 12 < d) ? colidx + sx + i + 12 : cdum);
        G0 = *(const bf16x8*)(vB + (size_t)ci8[0] * 8);
        G1 = *(const bf16x8*)(vB + (size_t)ci8[1] * 8);
        G2 = *(const bf16x8*)(vB + (size_t)ci8[2] * 8);
        G3 = *(const bf16x8*)(vB + (size_t)ci8[3] * 8);
#pragma unroll
        for (int k = 0; k < 8; k++)
            a[k] += ((float)H0[k] + (float)H1[k]) + ((float)H2[k] + (float)H3[k]);
    }
    if (r < N_NODES) {
        float res[8];
        res[0] = dv * a[0] + h0.x; res[1] = dv * a[1] + h0.y;
        res[2] = dv * a[2] + h0.z; res[3] = dv * a[3] + h0.w;
        res[4] = dv * a[4] + h1.x; res[5] = dv * a[5] + h1.y;
        res[6] = dv * a[6] + h1.z; res[7] = dv * a[7] + h1.w;
        if (final_it) {
            *(float4*)(outF + (size_t)r * NCLASS + 32) = (float4){res[0], res[1], res[2], res[3]};
            *(float4*)(outF + (size_t)r * NCLASS + 36) = (float4){res[4], res[5], res[6], res[7]};
        } else {
            bf16x8 o;
#pragma unroll
            for (int k = 0; k < 8; k++) o[k] = (bf16)res[k];
            *(bf16x8*)(oB + (size_t)r * 8) = o;
        }
    }
}

// ---------------- launch ----------------

extern "C" void kernel_launch(void* const* d_in, const int* in_sizes, int n_in,
                              void* d_out, int out_size, void* d_ws, size_t ws_size,
                              hipStream_t stream) {
    const float* x  = (const float*)d_in[0];
    const int*   ei = (const int*)d_in[1];
    const float* W1 = (const float*)d_in[2];
    const float* b1 = (const float*)d_in[3];
    const float* W2 = (const float*)d_in[4];
    const float* b2 = (const float*)d_in[5];
    const float* W3 = (const float*)d_in[6];
    const float* b3 = (const float*)d_in[7];
    float* out = (float*)d_out;
    const int* rows = ei;
    const int* cols = ei + N_EDGES;

    // workspace carve (bytes)
    char* p = (char*)d_ws;
    bf16* hid1 = (bf16*)p;                 p += (size_t)N_NODES * NHID * 2;       // 51.2 MB (alias: binned)
    bf16* hid2 = (bf16*)p;                 p += (size_t)N_NODES * NHID * 2;       // 51.2 MB
    float* hA  = (float*)p;                p += (size_t)N_NODES * 32 * 4;         // 12.8 MB
    float* hB  = (float*)p;                p += (size_t)N_NODES * 8 * 4;          // 3.2 MB
    bf16* vAi  = (bf16*)p;                 p += (size_t)(N_NODES + 1) * 32 * 2;   // 6.4 MB
    bf16* vA0  = (bf16*)p;                 p += (size_t)(N_NODES + 1) * 32 * 2;
    bf16* vA1  = (bf16*)p;                 p += (size_t)(N_NODES + 1) * 32 * 2;
    bf16* vBi  = (bf16*)p;                 p += (size_t)(N_NODES + 1) * 8 * 2;    // 1.6 MB
    bf16* vB0  = (bf16*)p;                 p += (size_t)(N_NODES + 1) * 8 * 2;
    bf16* vB1  = (bf16*)p;                 p += (size_t)(N_NODES + 1) * 8 * 2;
    bf16* W1b  = (bf16*)p;                 p += (size_t)NHID * NFEAT * 2;
    bf16* W2b  = (bf16*)p;                 p += (size_t)NHID * NHID * 2;
    bf16* W3p  = (bf16*)p;                 p += (size_t)64 * NHID * 2;
    float* b3p = (float*)p;                p += 64 * 4;
    int* bcnt    = (int*)p;                p += (size_t)NPAD * 4;
    int2* rowptr2 = (int2*)p;              p += (size_t)NPAD2 * 8;
    int* boff2   = (int*)p;                p += (size_t)N_NODES * 4;
    int* colidx  = (int*)p;                p += (size_t)COLN * 4;                 // 7.7 MB (padded)
    int* bsum    = (int*)p;                p += 512 * 4;
    float* dinv  = (float*)p;              p += (size_t)N_NODES * 4;

    int* btot  = bsum;          // 196 ints
    int* bbase = bsum + 256;    // 197 ints
    int* binned = (int*)hid1;   // 6.4 MB, dead before MLP starts

    // CSR build (rows padded to multiple of 4, 16B-aligned segments)
    bin_count<<<NBLK_BIN, 256, 0, stream>>>(rows, bcnt);
    bin_scan<<<NBUCK, 256, 0, stream>>>(bcnt, boff2, btot);
    base_scan<<<1, 256, 0, stream>>>(btot, bbase);
    bin_scatter<<<NBLK_BIN, 256, 0, stream>>>(rows, cols, boff2, bbase, binned);
    bucket_csr<<<NBUCK, 256, 0, stream>>>(binned, bbase, rowptr2, colidx, dinv);

    // weight conversion
    cvt_f2b<<<(NHID * NFEAT + 255) / 256, 256, 0, stream>>>(W1, W1b, NHID * NFEAT);
    cvt_f2b<<<(NHID * NHID + 255) / 256, 256, 0, stream>>>(W2, W2b, NHID * NHID);
    pad_w3<<<(64 * NHID) / 256, 256, 0, stream>>>(W3, b3, W3p, b3p);

    // MLP (deep-pipelined MFMA GEMM, barriers without vmcnt drain)
    {
        int M = N_NODES;
        int gy = (M + 127) / 128;
        gemm_mfma<128, float, true, 0><<<dim3(2, gy), 256, 0, stream>>>(
            x, W1b, b1, hid1, nullptr, nullptr, nullptr, nullptr, M, NFEAT, NHID);
        gemm_mfma<128, bf16, true, 0><<<dim3(2, gy), 256, 0, stream>>>(
            hid1, W2b, b2, hid2, nullptr, nullptr, nullptr, nullptr, M, NHID, NHID);
        gemm_mfma<64, bf16, false, 1><<<dim3(1, gy), 256, 0, stream>>>(
            hid2, W3p, b3p, nullptr, hA, hB, vAi, vBi, M, NHID, 64);
    }

    zero_dummy<<<1, 64, 0, stream>>>(vAi, vA0, vA1, vBi, vB0, vB1, colidx);

    // 10 power iterations: independent A-chain (32 cls) then B-chain (8 cls).
    // Separation keeps vB (1.6 MB) L2-resident during the B-chain.
    const bf16* sA = vAi;
    for (int it = 0; it < 10; it++) {
        int fin = (it == 9);
        bf16* dA = (it & 1) ? vA1 : vA0;
        spmm_A<<<BLK_A, 256, 0, stream>>>(sA, hA, rowptr2, colidx, dinv, dA, out, fin);
        sA = dA;
    }
    const bf16* sB = vBi;
    for (int it = 0; it < 10; it++) {
        int fin = (it == 9);
        bf16* dB = (it & 1) ? vB1 : vB0;
        spmm_B<<<BLK_B, 256, 0, stream>>>(sB, hB, rowptr2, colidx, dinv, dB, out, fin);
        sB = dB;
    }
}